// Round 5
// baseline (1105.985 us; speedup 1.0000x reference)
//
#include <hip/hip_runtime.h>
#include <math.h>

// Problem constants (fixed by setup_inputs)
constexpr int Bb = 128;   // batch
constexpr int Nn = 2048;  // input capsules
constexpr int Dd = 8;     // input capsule dim
constexpr int Jj = 32;    // output capsules
constexpr int Pp = 16;    // output capsule dim

// Tiling: 512-thread blocks, 8 waves, BT=2 batches/wave, shared n-slice.
// 512 blocks = 2/CU, 16 waves/CU. (R4-proven config.)
constexpr int BT = 2;
constexpr int WV = 8;
constexpr int BB = BT * WV;      // 16 batches per block
constexpr int BN = 32;           // n per block
constexpr int NBC = Bb / BB;     // 8
constexpr int NNC = Nn / BN;     // 64
constexpr int GRID = NBC * NNC;  // 512
constexpr int SZ = Bb * Jj * Pp;            // 65536 floats
constexpr int WSLICE_F4 = Jj * Pp * Dd / 4; // 1024 float4 per n-slice (16 KB)

typedef float v2f __attribute__((ext_vector_type(2)));

// Routing pass. W staged per-n in LDS (swizzled, conflict-free; verified
// SQ_LDS_BANK_CONFLICT==0), double buffered. XCD swizzle (verified R4:
// FETCH 139->26 MB): the 8 bc-sharers of an n-chunk share blockIdx&7.
// R5: LDS read addresses hoisted (nn-invariant), nn-loop unrolled x2 so the
// double-buffer base is compile-time, logit dot kept packed (one hadd/bb).
template<int LOGITS, int ATOMIC>
__global__ __launch_bounds__(512, 4)
void route_k(const float* __restrict__ x, const float* __restrict__ W,
             const float* __restrict__ OS, float* __restrict__ S)
{
    __shared__ float4 wbuf[2][WSLICE_F4];   // 2 x 16 KB W double buffer
    __shared__ float  xs[BB * BN * Dd];     // 16 KB x tile [b][n][d]

    const int tid  = threadIdx.x;
    const int wave = tid >> 6;
    const int lane = tid & 63;

    const int id  = blockIdx.x;
    const int xcd = id & 7;
    const int bc  = (id >> 3) & 7;
    const int nch = id >> 6;               // 0..7
    const int nc  = xcd + 8 * nch;         // 0..63
    const int b0  = bc * BB;
    const int n0  = nc * BN;
    const int j   = lane >> 1;
    const int hp  = lane & 1;              // p-half

    // ---- stage x tile: 16 b x 32 n x 8 d = 1024 float4, 2 per thread ----
    {
        const int b = tid >> 5, f = tid & 31;
        const float4* src = reinterpret_cast<const float4*>(
            x + ((size_t)(b0 + b) * Nn + n0) * Dd);
        float4* dst = reinterpret_cast<float4*>(xs + (size_t)b * BN * Dd);
        dst[f] = src[f];
        dst[f + 32] = src[f + 32];
    }

    // ---- W staging: slice = 1024 float4; thread t handles G = t, t+512 ----
    const float4* Wg = reinterpret_cast<const float4*>(W);
    const int col = tid & 31;    // within-j float4 column (p*2+dh)
    const int jlo = tid >> 5;    // j for G0 (0..15); G1 -> jlo+16
    const int kk  = tid & 15;    // swizzle k
    const int l0  = tid >> 4;    // swizzle l for G0; G1 -> l0+32

    float4 st[2];
    auto load_slice = [&](int n) {
        const size_t base = (size_t)n * 32 + col;
        st[0] = Wg[base + (size_t)jlo * ((size_t)Nn * 32)];
        st[1] = Wg[base + (size_t)(jlo + 16) * ((size_t)Nn * 32)];
    };
    // Store-side swizzle slots are tid-invariant: hoist.
    const int wslot0 = kk * 64 + ((l0 + kk) & 63);
    const int wslot1 = kk * 64 + ((l0 + 32 + kk) & 63);
    auto store_slice = [&](int buf) {
        wbuf[buf][wslot0] = st[0];
        wbuf[buf][wslot1] = st[1];
    };

    // Read-side swizzled indices: nn-invariant, hoisted (16 VGPRs).
    int widx[16];
    #pragma unroll
    for (int k = 0; k < 16; ++k) widx[k] = k * 64 + ((lane + k) & 63);

    // Output-sum fragment for logits
    float osum[BT][8];
    if (LOGITS) {
        #pragma unroll
        for (int bb = 0; bb < BT; ++bb) {
            const float4* op = reinterpret_cast<const float4*>(
                OS + ((size_t)(b0 + wave * BT + bb) * Jj + j) * Pp + hp * 8);
            float4 a = op[0], b4 = op[1];
            osum[bb][0] = a.x;  osum[bb][1] = a.y;  osum[bb][2] = a.z;  osum[bb][3] = a.w;
            osum[bb][4] = b4.x; osum[bb][5] = b4.y; osum[bb][6] = b4.z; osum[bb][7] = b4.w;
        }
    }

    float Sa[BT][8];
    #pragma unroll
    for (int bb = 0; bb < BT; ++bb)
        #pragma unroll
        for (int pp = 0; pp < 8; ++pp) Sa[bb][pp] = 0.f;

    load_slice(n0);
    store_slice(0);
    __syncthreads();

    const float* xw = xs + (size_t)(wave * BT) * BN * Dd;  // this wave's x rows

    #pragma unroll 2
    for (int nn = 0; nn < BN; ++nn) {
        if (nn + 1 < BN) load_slice(n0 + nn + 1);  // prefetch next slice to regs
        const int buf = nn & 1;   // compile-time under unroll-2

        // x values (LDS broadcast) as float2 pairs for v_pk_fma_f32
        v2f xv[BT][4];
        #pragma unroll
        for (int bb = 0; bb < BT; ++bb) {
            const v2f* xp = reinterpret_cast<const v2f*>(
                xw + ((size_t)bb * BN + nn) * Dd);
            #pragma unroll
            for (int d = 0; d < 4; ++d) xv[bb][d] = xp[d];
        }

        // u_hat (kept as v2f d-pair partials; hadd deferred)
        v2f uh2[BT][8];
        #pragma unroll
        for (int pp = 0; pp < 8; ++pp) {
            float4 a = wbuf[buf][widx[2 * pp]];
            float4 b = wbuf[buf][widx[2 * pp + 1]];
            v2f wv0 = {a.x, a.y}, wv1 = {a.z, a.w};
            v2f wv2 = {b.x, b.y}, wv3 = {b.z, b.w};
            #pragma unroll
            for (int bb = 0; bb < BT; ++bb) {
                v2f acc = wv0 * xv[bb][0];
                acc = __builtin_elementwise_fma(wv1, xv[bb][1], acc);
                acc = __builtin_elementwise_fma(wv2, xv[bb][2], acc);
                acc = __builtin_elementwise_fma(wv3, xv[bb][3], acc);
                uh2[bb][pp] = acc;
            }
        }

        if (!LOGITS) {
            #pragma unroll
            for (int bb = 0; bb < BT; ++bb)
                #pragma unroll
                for (int pp = 0; pp < 8; ++pp) {
                    Sa[bb][pp] += uh2[bb][pp].x + uh2[bb][pp].y;
                }
        } else {
            #pragma unroll
            for (int bb = 0; bb < BT; ++bb) {
                // packed logit dot: lg2 accumulates both d-halves
                v2f lg2 = {0.f, 0.f};
                #pragma unroll
                for (int pp = 0; pp < 8; ++pp) {
                    v2f os2 = {osum[bb][pp], osum[bb][pp]};  // op_sel-able
                    lg2 = __builtin_elementwise_fma(os2, uh2[bb][pp], lg2);
                }
                float lg = lg2.x + lg2.y;      // one hadd per bb
                lg += __shfl_xor(lg, 1, 64);   // merge p-halves: full 16-p dot
                // softmax over j (no max-subtract; |lg| small): butterfly
                float e = __expf(lg);
                float se = e;
                #pragma unroll
                for (int mk = 2; mk <= 32; mk <<= 1)
                    se += __shfl_xor(se, mk, 64);
                float c = e * __builtin_amdgcn_rcpf(se);
                #pragma unroll
                for (int pp = 0; pp < 8; ++pp)
                    Sa[bb][pp] = fmaf(c, uh2[bb][pp].x + uh2[bb][pp].y,
                                      Sa[bb][pp]);
            }
        }

        if (nn + 1 < BN) {
            store_slice((nn + 1) & 1);
            __syncthreads();
        }
    }

    // ---- flush block-partial S ----
    #pragma unroll
    for (int bb = 0; bb < BT; ++bb) {
        const size_t off = ((size_t)(b0 + wave * BT + bb) * Jj + j) * Pp + hp * 8;
        if (ATOMIC) {
            float* sp = S + off;
            #pragma unroll
            for (int pp = 0; pp < 8; ++pp) atomicAdd(sp + pp, Sa[bb][pp]);
        } else {
            float4* dst = reinterpret_cast<float4*>(S + (size_t)nc * SZ + off);
            dst[0] = make_float4(Sa[bb][0], Sa[bb][1], Sa[bb][2], Sa[bb][3]);
            dst[1] = make_float4(Sa[bb][4], Sa[bb][5], Sa[bb][6], Sa[bb][7]);
        }
    }
}

// Reduce nparts partial S slices, then squash.
// mode 0: OS = v; 1: OS += v; 2: out = v.  One thread per float4 (16384).
__global__ void reduce_squash_k(const float* __restrict__ Sp, int nparts,
                                float scale, float* __restrict__ OS,
                                float* __restrict__ out, int mode)
{
    const int t = blockIdx.x * 256 + threadIdx.x;   // 0..16383
    const float4* sp = reinterpret_cast<const float4*>(Sp);
    float4 a = make_float4(0.f, 0.f, 0.f, 0.f);
    #pragma unroll 4
    for (int s = 0; s < nparts; ++s) {
        float4 v = sp[(size_t)s * (SZ / 4) + t];
        a.x += v.x; a.y += v.y; a.z += v.z; a.w += v.w;
    }
    a.x *= scale; a.y *= scale; a.z *= scale; a.w *= scale;
    float s2 = a.x * a.x + a.y * a.y + a.z * a.z + a.w * a.w;
    s2 += __shfl_xor(s2, 1, 64);   // 16 p = 4 consecutive threads
    s2 += __shfl_xor(s2, 2, 64);
    const float g = s2 / ((1.f + s2) * sqrtf(s2 + 1e-7f));
    float4 v = make_float4(g * a.x, g * a.y, g * a.z, g * a.w);
    if (mode == 0) {
        reinterpret_cast<float4*>(OS)[t] = v;
    } else if (mode == 1) {
        float4 o = reinterpret_cast<float4*>(OS)[t];
        o.x += v.x; o.y += v.y; o.z += v.z; o.w += v.w;
        reinterpret_cast<float4*>(OS)[t] = o;
    } else {
        reinterpret_cast<float4*>(out)[t] = v;
    }
}

extern "C" void kernel_launch(void* const* d_in, const int* in_sizes, int n_in,
                              void* d_out, int out_size, void* d_ws, size_t ws_size,
                              hipStream_t stream)
{
    const float* x = (const float*)d_in[0];   // [128, 2048, 8]
    const float* W = (const float*)d_in[1];   // [32, 2048, 16, 8]
    float* out = (float*)d_out;               // [128, 32, 16]

    const bool part = ws_size >= (size_t)(NNC + 1) * SZ * sizeof(float); // 16.9 MB
    dim3 rg(GRID), rb(512);
    dim3 sg(SZ / 4 / 256), sb(256);           // 64 blocks x 256

    if (part) {
        float* Sp = (float*)d_ws;                 // [64][65536] partials
        float* OS = Sp + (size_t)NNC * SZ;

        route_k<0, 0><<<rg, rb, 0, stream>>>(x, W, nullptr, Sp);
        reduce_squash_k<<<sg, sb, 0, stream>>>(Sp, NNC, 1.f / Jj, OS, out, 0);

        route_k<1, 0><<<rg, rb, 0, stream>>>(x, W, OS, Sp);
        reduce_squash_k<<<sg, sb, 0, stream>>>(Sp, NNC, 1.f, OS, out, 1);

        route_k<1, 0><<<rg, rb, 0, stream>>>(x, W, OS, Sp);
        reduce_squash_k<<<sg, sb, 0, stream>>>(Sp, NNC, 1.f, OS, out, 2);
    } else {
        float* S  = (float*)d_ws;
        float* OS = S + SZ;
        const size_t Sbytes = (size_t)SZ * sizeof(float);

        hipMemsetAsync(S, 0, Sbytes, stream);
        route_k<0, 1><<<rg, rb, 0, stream>>>(x, W, nullptr, S);
        reduce_squash_k<<<sg, sb, 0, stream>>>(S, 1, 1.f / Jj, OS, out, 0);

        hipMemsetAsync(S, 0, Sbytes, stream);
        route_k<1, 1><<<rg, rb, 0, stream>>>(x, W, OS, S);
        reduce_squash_k<<<sg, sb, 0, stream>>>(S, 1, 1.f, OS, out, 1);

        hipMemsetAsync(S, 0, Sbytes, stream);
        route_k<1, 1><<<rg, rb, 0, stream>>>(x, W, OS, S);
        reduce_squash_k<<<sg, sb, 0, stream>>>(S, 1, 1.f, OS, out, 2);
    }
}

// Round 6
// 450.062 us; speedup vs baseline: 2.4574x; 2.4574x over previous
//
#include <hip/hip_runtime.h>
#include <math.h>

// Problem constants (fixed by setup_inputs)
constexpr int Bb = 128;   // batch
constexpr int Nn = 2048;  // input capsules
constexpr int Dd = 8;     // input capsule dim
constexpr int Jj = 32;    // output capsules
constexpr int Pp = 16;    // output capsule dim

// Tiling: 256-thread blocks, 4 waves, BT=4 batches/wave (halves LDS W-traffic
// vs BT=2), shared n-slice. GRID=512, LDS 48 KB -> 3 blocks/CU = 12 waves/CU.
constexpr int BT = 4;
constexpr int WV = 4;
constexpr int BB = BT * WV;      // 16 batches per block
constexpr int BN = 32;           // n per block
constexpr int NBC = Bb / BB;     // 8
constexpr int NNC = Nn / BN;     // 64
constexpr int GRID = NBC * NNC;  // 512
constexpr int SZ = Bb * Jj * Pp;            // 65536 floats
constexpr int WSLICE_F4 = Jj * Pp * Dd / 4; // 1024 float4 per n-slice (16 KB)

typedef float v2f __attribute__((ext_vector_type(2)));

// Routing pass. W staged per-n in LDS (swizzled, conflict-free; verified
// SQ_LDS_BANK_CONFLICT==0 in R2/R4), double buffered. XCD swizzle (verified
// R4: FETCH 139->26 MB): the 8 bc-sharers of an n-chunk share blockIdx&7.
// R6: R4 code shape verbatim (no hoisted index arrays, no unroll pragmas --
// R5 proved those spill to scratch: WRITE 25 MB -> 1.39 GB), decomposition
// moved to BT=4/WV=4 (R2's proven-no-spill register shape, 72 VGPRs).
template<int LOGITS, int ATOMIC>
__global__ __launch_bounds__(256, 3)
void route_k(const float* __restrict__ x, const float* __restrict__ W,
             const float* __restrict__ OS, float* __restrict__ S)
{
    __shared__ float4 wbuf[2][WSLICE_F4];   // 2 x 16 KB W double buffer
    __shared__ float  xs[BB * BN * Dd];     // 16 KB x tile [b][n][d]

    const int tid  = threadIdx.x;
    const int wave = tid >> 6;
    const int lane = tid & 63;

    const int id  = blockIdx.x;
    const int xcd = id & 7;
    const int bc  = (id >> 3) & 7;
    const int nch = id >> 6;               // 0..7
    const int nc  = xcd + 8 * nch;         // 0..63
    const int b0  = bc * BB;
    const int n0  = nc * BN;
    const int j   = lane >> 1;
    const int hp  = lane & 1;              // p-half

    // ---- stage x tile: 16 b x 32 n x 8 d = 1024 float4, 4 per thread ----
    {
        const int b = tid >> 4, f = tid & 15;
        const float4* src = reinterpret_cast<const float4*>(
            x + ((size_t)(b0 + b) * Nn + n0) * Dd);
        float4* dst = reinterpret_cast<float4*>(xs + (size_t)b * BN * Dd);
        #pragma unroll
        for (int i = 0; i < 4; ++i) dst[f + 16 * i] = src[f + 16 * i];
    }

    // ---- W staging: slice = 1024 float4; thread t handles G = t + 256c ----
    const float4* Wg = reinterpret_cast<const float4*>(W);
    const int tg = tid & 31;    // within-j float4 column (p*2+dh)
    const int th = tid >> 5;    // j base (0..7); chunk c -> j = th + 8c
    const int kk = tid & 15;    // swizzle k
    const int lb = tid >> 4;    // swizzle l base (0..15); chunk c -> l = lb+16c

    float4 st[4];
    auto load_slice = [&](int n) {
        const size_t base = (size_t)n * 32 + tg;
        #pragma unroll
        for (int c = 0; c < 4; ++c)
            st[c] = Wg[base + (size_t)(th + 8 * c) * ((size_t)Nn * 32)];
    };
    auto store_slice = [&](int buf) {
        #pragma unroll
        for (int c = 0; c < 4; ++c)
            wbuf[buf][kk * 64 + ((lb + 16 * c + kk) & 63)] = st[c];
    };

    // Output-sum fragment for logits
    float osum[BT][8];
    if (LOGITS) {
        #pragma unroll
        for (int bb = 0; bb < BT; ++bb) {
            const float4* op = reinterpret_cast<const float4*>(
                OS + ((size_t)(b0 + wave * BT + bb) * Jj + j) * Pp + hp * 8);
            float4 a = op[0], b4 = op[1];
            osum[bb][0] = a.x;  osum[bb][1] = a.y;  osum[bb][2] = a.z;  osum[bb][3] = a.w;
            osum[bb][4] = b4.x; osum[bb][5] = b4.y; osum[bb][6] = b4.z; osum[bb][7] = b4.w;
        }
    }

    float Sa[BT][8];
    #pragma unroll
    for (int bb = 0; bb < BT; ++bb)
        #pragma unroll
        for (int pp = 0; pp < 8; ++pp) Sa[bb][pp] = 0.f;

    load_slice(n0);
    store_slice(0);
    __syncthreads();

    const float* xw = xs + (size_t)(wave * BT) * BN * Dd;  // this wave's x rows

    for (int nn = 0; nn < BN; ++nn) {
        if (nn + 1 < BN) load_slice(n0 + nn + 1);  // prefetch next slice to regs
        const int buf = nn & 1;

        // x values (LDS broadcast) as float2 pairs for v_pk_fma_f32
        v2f xv[BT][4];
        #pragma unroll
        for (int bb = 0; bb < BT; ++bb) {
            const v2f* xp = reinterpret_cast<const v2f*>(
                xw + ((size_t)bb * BN + nn) * Dd);
            #pragma unroll
            for (int d = 0; d < 4; ++d) xv[bb][d] = xp[d];
        }

        // u_hat from swizzled LDS W fragments
        float uh[BT][8];
        #pragma unroll
        for (int pp = 0; pp < 8; ++pp) {
            const int k0 = 2 * pp, k1 = 2 * pp + 1;
            float4 a = wbuf[buf][k0 * 64 + ((lane + k0) & 63)];
            float4 b = wbuf[buf][k1 * 64 + ((lane + k1) & 63)];
            v2f wv0 = {a.x, a.y}, wv1 = {a.z, a.w};
            v2f wv2 = {b.x, b.y}, wv3 = {b.z, b.w};
            #pragma unroll
            for (int bb = 0; bb < BT; ++bb) {
                v2f acc = wv0 * xv[bb][0];
                acc = __builtin_elementwise_fma(wv1, xv[bb][1], acc);
                acc = __builtin_elementwise_fma(wv2, xv[bb][2], acc);
                acc = __builtin_elementwise_fma(wv3, xv[bb][3], acc);
                uh[bb][pp] = acc.x + acc.y;
            }
        }

        if (!LOGITS) {
            #pragma unroll
            for (int bb = 0; bb < BT; ++bb)
                #pragma unroll
                for (int pp = 0; pp < 8; ++pp) Sa[bb][pp] += uh[bb][pp];
        } else {
            #pragma unroll
            for (int bb = 0; bb < BT; ++bb) {
                float lg = 0.f;
                #pragma unroll
                for (int pp = 0; pp < 8; ++pp)
                    lg = fmaf(osum[bb][pp], uh[bb][pp], lg);
                lg += __shfl_xor(lg, 1, 64);   // merge p-halves: full 16-p dot
                // softmax over j (no max-subtract; |lg| small): butterfly
                float e = __expf(lg);
                float se = e;
                #pragma unroll
                for (int mk = 2; mk <= 32; mk <<= 1)
                    se += __shfl_xor(se, mk, 64);
                float c = e * __builtin_amdgcn_rcpf(se);
                #pragma unroll
                for (int pp = 0; pp < 8; ++pp)
                    Sa[bb][pp] = fmaf(c, uh[bb][pp], Sa[bb][pp]);
            }
        }

        if (nn + 1 < BN) {
            store_slice((nn + 1) & 1);
            __syncthreads();
        }
    }

    // ---- flush block-partial S ----
    #pragma unroll
    for (int bb = 0; bb < BT; ++bb) {
        const size_t off = ((size_t)(b0 + wave * BT + bb) * Jj + j) * Pp + hp * 8;
        if (ATOMIC) {
            float* sp = S + off;
            #pragma unroll
            for (int pp = 0; pp < 8; ++pp) atomicAdd(sp + pp, Sa[bb][pp]);
        } else {
            float4* dst = reinterpret_cast<float4*>(S + (size_t)nc * SZ + off);
            dst[0] = make_float4(Sa[bb][0], Sa[bb][1], Sa[bb][2], Sa[bb][3]);
            dst[1] = make_float4(Sa[bb][4], Sa[bb][5], Sa[bb][6], Sa[bb][7]);
        }
    }
}

// Reduce nparts partial S slices, then squash.
// mode 0: OS = v; 1: OS += v; 2: out = v.  One thread per float4 (16384).
__global__ void reduce_squash_k(const float* __restrict__ Sp, int nparts,
                                float scale, float* __restrict__ OS,
                                float* __restrict__ out, int mode)
{
    const int t = blockIdx.x * 256 + threadIdx.x;   // 0..16383
    const float4* sp = reinterpret_cast<const float4*>(Sp);
    float4 a = make_float4(0.f, 0.f, 0.f, 0.f);
    #pragma unroll 4
    for (int s = 0; s < nparts; ++s) {
        float4 v = sp[(size_t)s * (SZ / 4) + t];
        a.x += v.x; a.y += v.y; a.z += v.z; a.w += v.w;
    }
    a.x *= scale; a.y *= scale; a.z *= scale; a.w *= scale;
    float s2 = a.x * a.x + a.y * a.y + a.z * a.z + a.w * a.w;
    s2 += __shfl_xor(s2, 1, 64);   // 16 p = 4 consecutive threads
    s2 += __shfl_xor(s2, 2, 64);
    const float g = s2 / ((1.f + s2) * sqrtf(s2 + 1e-7f));
    float4 v = make_float4(g * a.x, g * a.y, g * a.z, g * a.w);
    if (mode == 0) {
        reinterpret_cast<float4*>(OS)[t] = v;
    } else if (mode == 1) {
        float4 o = reinterpret_cast<float4*>(OS)[t];
        o.x += v.x; o.y += v.y; o.z += v.z; o.w += v.w;
        reinterpret_cast<float4*>(OS)[t] = o;
    } else {
        reinterpret_cast<float4*>(out)[t] = v;
    }
}

extern "C" void kernel_launch(void* const* d_in, const int* in_sizes, int n_in,
                              void* d_out, int out_size, void* d_ws, size_t ws_size,
                              hipStream_t stream)
{
    const float* x = (const float*)d_in[0];   // [128, 2048, 8]
    const float* W = (const float*)d_in[1];   // [32, 2048, 16, 8]
    float* out = (float*)d_out;               // [128, 32, 16]

    const bool part = ws_size >= (size_t)(NNC + 1) * SZ * sizeof(float); // 16.9 MB
    dim3 rg(GRID), rb(256);
    dim3 sg(SZ / 4 / 256), sb(256);           // 64 blocks x 256

    if (part) {
        float* Sp = (float*)d_ws;                 // [64][65536] partials
        float* OS = Sp + (size_t)NNC * SZ;

        route_k<0, 0><<<rg, rb, 0, stream>>>(x, W, nullptr, Sp);
        reduce_squash_k<<<sg, sb, 0, stream>>>(Sp, NNC, 1.f / Jj, OS, out, 0);

        route_k<1, 0><<<rg, rb, 0, stream>>>(x, W, OS, Sp);
        reduce_squash_k<<<sg, sb, 0, stream>>>(Sp, NNC, 1.f, OS, out, 1);

        route_k<1, 0><<<rg, rb, 0, stream>>>(x, W, OS, Sp);
        reduce_squash_k<<<sg, sb, 0, stream>>>(Sp, NNC, 1.f, OS, out, 2);
    } else {
        float* S  = (float*)d_ws;
        float* OS = S + SZ;
        const size_t Sbytes = (size_t)SZ * sizeof(float);

        hipMemsetAsync(S, 0, Sbytes, stream);
        route_k<0, 1><<<rg, rb, 0, stream>>>(x, W, nullptr, S);
        reduce_squash_k<<<sg, sb, 0, stream>>>(S, 1, 1.f / Jj, OS, out, 0);

        hipMemsetAsync(S, 0, Sbytes, stream);
        route_k<1, 1><<<rg, rb, 0, stream>>>(x, W, OS, S);
        reduce_squash_k<<<sg, sb, 0, stream>>>(S, 1, 1.f, OS, out, 1);

        hipMemsetAsync(S, 0, Sbytes, stream);
        route_k<1, 1><<<rg, rb, 0, stream>>>(x, W, OS, S);
        reduce_squash_k<<<sg, sb, 0, stream>>>(S, 1, 1.f, OS, out, 2);
    }
}

// Round 7
// 222.282 us; speedup vs baseline: 4.9756x; 2.0247x over previous
//
#include <hip/hip_runtime.h>
#include <math.h>

// Problem constants (fixed by setup_inputs)
constexpr int Bb = 128;   // batch
constexpr int Nn = 2048;  // input capsules
constexpr int Dd = 8;     // input capsule dim
constexpr int Jj = 32;    // output capsules
constexpr int Pp = 16;    // output capsule dim

// Tiling: R4-proven config. 512-thread blocks, 8 waves, BT=2 batches/wave.
// GRID=512 -> 2 blocks/CU, 16 waves/CU.
constexpr int BT = 2;
constexpr int WV = 8;
constexpr int BB = BT * WV;      // 16 batches per block
constexpr int BN = 32;           // n per block
constexpr int NBC = Bb / BB;     // 8
constexpr int NNC = Nn / BN;     // 64
constexpr int GRID = NBC * NNC;  // 512
constexpr int SZ = Bb * Jj * Pp; // 65536 floats

typedef _Float16 half2v __attribute__((ext_vector_type(2)));

#if __has_builtin(__builtin_amdgcn_fdot2)
__device__ inline float fdot2(half2v a, half2v b, float c) {
    return __builtin_amdgcn_fdot2(a, b, c, false);
}
#else
__device__ inline float fdot2(half2v a, half2v b, float c) {
    return (float)a.x * (float)b.x + (float)a.y * (float)b.y + c;
}
#endif

__device__ inline half2v bch2(unsigned u) { return __builtin_bit_cast(half2v, u); }
__device__ inline unsigned pkh2(float lo, float hi) {
    half2v h; h.x = (_Float16)lo; h.y = (_Float16)hi;   // v_cvt_f16_f32 (RTN)
    return __builtin_bit_cast(unsigned, h);
}

// Routing pass. W staged per-n in LDS as fp16 (8 KB/slice, double-buffered),
// x tile fp16. u_hat via v_dot2_f32_f16 (f16 mul, fp32 accumulate).
// Swizzled W layout (mirrors R2/R4's proven-zero-conflict pattern):
//   16B chunk for (l = j*2+hp, pp) at slot pp*64 + ((l+pp)&63).
// XCD swizzle (verified R4: FETCH 139->26 MB): 8 bc-sharers share blockIdx&7.
// R5/R6 lessons: no hoisted index arrays, no unroll pragmas, BT=2 only.
template<int LOGITS, int ATOMIC>
__global__ __launch_bounds__(512, 4)
void route_k(const float* __restrict__ x, const float* __restrict__ W,
             const float* __restrict__ OS, float* __restrict__ S)
{
    __shared__ uint4 wbuf[2][512];   // 2 x 8 KB fp16 W double buffer
    __shared__ uint4 xs[BB * BN];    // 8 KB fp16 x tile: [b][n] -> 8 halves

    const int tid  = threadIdx.x;
    const int wave = tid >> 6;
    const int lane = tid & 63;

    const int id  = blockIdx.x;
    const int xcd = id & 7;
    const int bc  = (id >> 3) & 7;
    const int nch = id >> 6;               // 0..7
    const int nc  = xcd + 8 * nch;         // 0..63
    const int b0  = bc * BB;
    const int n0  = nc * BN;
    const int j   = lane >> 1;
    const int hp  = lane & 1;              // p-half

    // ---- stage x tile as fp16: thread t -> (b = t>>5, n = t&31) ----
    {
        const int b = tid >> 5, n = tid & 31;
        const float4* src = reinterpret_cast<const float4*>(
            x + ((size_t)(b0 + b) * Nn + n0 + n) * Dd);
        float4 a = src[0], c4 = src[1];
        uint4 o;
        o.x = pkh2(a.x, a.y);  o.y = pkh2(a.z, a.w);
        o.z = pkh2(c4.x, c4.y); o.w = pkh2(c4.z, c4.w);
        xs[b * BN + n] = o;
    }

    // ---- W staging: thread t -> (j = t>>4, p = t&15); 2 float4 -> 1 uint4 ----
    const float4* Wg = reinterpret_cast<const float4*>(W);
    const int sj = tid >> 4;          // j
    const int sp = tid & 15;          // p
    const int sl = sj * 2 + (sp >> 3);          // l for this chunk
    const int spp = sp & 7;                     // pp
    const int wslot = spp * 64 + ((sl + spp) & 63);

    float4 sta, stb;
    auto load_slice = [&](int n) {
        const size_t base = (size_t)n * 32 + sp * 2 + (size_t)sj * ((size_t)Nn * 32);
        sta = Wg[base];
        stb = Wg[base + 1];
    };
    auto store_slice = [&](int buf) {
        uint4 o;
        o.x = pkh2(sta.x, sta.y);  o.y = pkh2(sta.z, sta.w);
        o.z = pkh2(stb.x, stb.y);  o.w = pkh2(stb.z, stb.w);
        wbuf[buf][wslot] = o;
    };

    // Output-sum fragment for logits
    float osum[BT][8];
    if (LOGITS) {
        #pragma unroll
        for (int bb = 0; bb < BT; ++bb) {
            const float4* op = reinterpret_cast<const float4*>(
                OS + ((size_t)(b0 + wave * BT + bb) * Jj + j) * Pp + hp * 8);
            float4 a = op[0], b4 = op[1];
            osum[bb][0] = a.x;  osum[bb][1] = a.y;  osum[bb][2] = a.z;  osum[bb][3] = a.w;
            osum[bb][4] = b4.x; osum[bb][5] = b4.y; osum[bb][6] = b4.z; osum[bb][7] = b4.w;
        }
    }

    float Sa[BT][8];
    #pragma unroll
    for (int bb = 0; bb < BT; ++bb)
        #pragma unroll
        for (int pp = 0; pp < 8; ++pp) Sa[bb][pp] = 0.f;

    load_slice(n0);
    store_slice(0);
    __syncthreads();

    const uint4* xw = xs + (size_t)(wave * BT) * BN;   // this wave's x rows

    for (int nn = 0; nn < BN; ++nn) {
        if (nn + 1 < BN) load_slice(n0 + nn + 1);  // prefetch next slice to regs
        const int buf = nn & 1;

        // x rows (LDS broadcast, one b128 per batch): 8 halves = 4 half2
        half2v x01[BT], x23[BT], x45[BT], x67[BT];
        #pragma unroll
        for (int bb = 0; bb < BT; ++bb) {
            uint4 xr = xw[(size_t)bb * BN + nn];
            x01[bb] = bch2(xr.x); x23[bb] = bch2(xr.y);
            x45[bb] = bch2(xr.z); x67[bb] = bch2(xr.w);
        }

        // u_hat via fdot2 (f16 inputs, fp32 accumulate); no hadds needed
        float uh[BT][8];
        #pragma unroll
        for (int pp = 0; pp < 8; ++pp) {
            uint4 wv = wbuf[buf][pp * 64 + ((lane + pp) & 63)];
            half2v w01 = bch2(wv.x), w23 = bch2(wv.y);
            half2v w45 = bch2(wv.z), w67 = bch2(wv.w);
            #pragma unroll
            for (int bb = 0; bb < BT; ++bb) {
                float acc = fdot2(w01, x01[bb], 0.f);
                acc = fdot2(w23, x23[bb], acc);
                acc = fdot2(w45, x45[bb], acc);
                acc = fdot2(w67, x67[bb], acc);
                uh[bb][pp] = acc;
            }
        }

        if (!LOGITS) {
            #pragma unroll
            for (int bb = 0; bb < BT; ++bb)
                #pragma unroll
                for (int pp = 0; pp < 8; ++pp) Sa[bb][pp] += uh[bb][pp];
        } else {
            #pragma unroll
            for (int bb = 0; bb < BT; ++bb) {
                float lg = 0.f;
                #pragma unroll
                for (int pp = 0; pp < 8; ++pp)
                    lg = fmaf(osum[bb][pp], uh[bb][pp], lg);
                lg += __shfl_xor(lg, 1, 64);   // merge p-halves: full 16-p dot
                // softmax over j (no max-subtract; |lg| small): butterfly
                float e = __expf(lg);
                float se = e;
                #pragma unroll
                for (int mk = 2; mk <= 32; mk <<= 1)
                    se += __shfl_xor(se, mk, 64);
                float c = e * __builtin_amdgcn_rcpf(se);
                #pragma unroll
                for (int pp = 0; pp < 8; ++pp)
                    Sa[bb][pp] = fmaf(c, uh[bb][pp], Sa[bb][pp]);
            }
        }

        if (nn + 1 < BN) {
            store_slice((nn + 1) & 1);
            __syncthreads();
        }
    }

    // ---- flush block-partial S ----
    #pragma unroll
    for (int bb = 0; bb < BT; ++bb) {
        const size_t off = ((size_t)(b0 + wave * BT + bb) * Jj + j) * Pp + hp * 8;
        if (ATOMIC) {
            float* sp = S + off;
            #pragma unroll
            for (int pp = 0; pp < 8; ++pp) atomicAdd(sp + pp, Sa[bb][pp]);
        } else {
            float4* dst = reinterpret_cast<float4*>(S + (size_t)nc * SZ + off);
            dst[0] = make_float4(Sa[bb][0], Sa[bb][1], Sa[bb][2], Sa[bb][3]);
            dst[1] = make_float4(Sa[bb][4], Sa[bb][5], Sa[bb][6], Sa[bb][7]);
        }
    }
}

// Reduce nparts partial S slices, then squash.
// mode 0: OS = v; 1: OS += v; 2: out = v.  One thread per float4 (16384).
__global__ void reduce_squash_k(const float* __restrict__ Sp, int nparts,
                                float scale, float* __restrict__ OS,
                                float* __restrict__ out, int mode)
{
    const int t = blockIdx.x * 256 + threadIdx.x;   // 0..16383
    const float4* sp = reinterpret_cast<const float4*>(Sp);
    float4 a = make_float4(0.f, 0.f, 0.f, 0.f);
    #pragma unroll 4
    for (int s = 0; s < nparts; ++s) {
        float4 v = sp[(size_t)s * (SZ / 4) + t];
        a.x += v.x; a.y += v.y; a.z += v.z; a.w += v.w;
    }
    a.x *= scale; a.y *= scale; a.z *= scale; a.w *= scale;
    float s2 = a.x * a.x + a.y * a.y + a.z * a.z + a.w * a.w;
    s2 += __shfl_xor(s2, 1, 64);   // 16 p = 4 consecutive threads
    s2 += __shfl_xor(s2, 2, 64);
    const float g = s2 / ((1.f + s2) * sqrtf(s2 + 1e-7f));
    float4 v = make_float4(g * a.x, g * a.y, g * a.z, g * a.w);
    if (mode == 0) {
        reinterpret_cast<float4*>(OS)[t] = v;
    } else if (mode == 1) {
        float4 o = reinterpret_cast<float4*>(OS)[t];
        o.x += v.x; o.y += v.y; o.z += v.z; o.w += v.w;
        reinterpret_cast<float4*>(OS)[t] = o;
    } else {
        reinterpret_cast<float4*>(out)[t] = v;
    }
}

extern "C" void kernel_launch(void* const* d_in, const int* in_sizes, int n_in,
                              void* d_out, int out_size, void* d_ws, size_t ws_size,
                              hipStream_t stream)
{
    const float* x = (const float*)d_in[0];   // [128, 2048, 8]
    const float* W = (const float*)d_in[1];   // [32, 2048, 16, 8]
    float* out = (float*)d_out;               // [128, 32, 16]

    const bool part = ws_size >= (size_t)(NNC + 1) * SZ * sizeof(float); // 16.9 MB
    dim3 rg(GRID), rb(512);
    dim3 sg(SZ / 4 / 256), sb(256);           // 64 blocks x 256

    if (part) {
        float* Sp = (float*)d_ws;                 // [64][65536] partials
        float* OS = Sp + (size_t)NNC * SZ;

        route_k<0, 0><<<rg, rb, 0, stream>>>(x, W, nullptr, Sp);
        reduce_squash_k<<<sg, sb, 0, stream>>>(Sp, NNC, 1.f / Jj, OS, out, 0);

        route_k<1, 0><<<rg, rb, 0, stream>>>(x, W, OS, Sp);
        reduce_squash_k<<<sg, sb, 0, stream>>>(Sp, NNC, 1.f, OS, out, 1);

        route_k<1, 0><<<rg, rb, 0, stream>>>(x, W, OS, Sp);
        reduce_squash_k<<<sg, sb, 0, stream>>>(Sp, NNC, 1.f, OS, out, 2);
    } else {
        float* S  = (float*)d_ws;
        float* OS = S + SZ;
        const size_t Sbytes = (size_t)SZ * sizeof(float);

        hipMemsetAsync(S, 0, Sbytes, stream);
        route_k<0, 1><<<rg, rb, 0, stream>>>(x, W, nullptr, S);
        reduce_squash_k<<<sg, sb, 0, stream>>>(S, 1, 1.f / Jj, OS, out, 0);

        hipMemsetAsync(S, 0, Sbytes, stream);
        route_k<1, 1><<<rg, rb, 0, stream>>>(x, W, OS, S);
        reduce_squash_k<<<sg, sb, 0, stream>>>(S, 1, 1.f, OS, out, 1);

        hipMemsetAsync(S, 0, Sbytes, stream);
        route_k<1, 1><<<rg, rb, 0, stream>>>(x, W, OS, S);
        reduce_squash_k<<<sg, sb, 0, stream>>>(S, 1, 1.f, OS, out, 2);
    }
}

// Round 9
// 221.161 us; speedup vs baseline: 5.0008x; 1.0051x over previous
//
#include <hip/hip_runtime.h>
#include <math.h>

// Problem constants (fixed by setup_inputs)
constexpr int Bb = 128;   // batch
constexpr int Nn = 2048;  // input capsules
constexpr int Dd = 8;     // input capsule dim
constexpr int Jj = 32;    // output capsules
constexpr int Pp = 16;    // output capsule dim

// Tiling: R4/R7-proven config. 512-thread blocks, 8 waves, BT=2 batches/wave.
// GRID=512 -> 2 blocks/CU, 16 waves/CU.
constexpr int BT = 2;
constexpr int WV = 8;
constexpr int BB = BT * WV;      // 16 batches per block
constexpr int BN = 32;           // n per block
constexpr int NBC = Bb / BB;     // 8
constexpr int NNC = Nn / BN;     // 64
constexpr int GRID = NBC * NNC;  // 512
constexpr int SZ = Bb * Jj * Pp; // 65536 floats

typedef _Float16 half2v __attribute__((ext_vector_type(2)));

#if __has_builtin(__builtin_amdgcn_fdot2)
__device__ inline float fdot2(half2v a, half2v b, float c) {
    return __builtin_amdgcn_fdot2(a, b, c, false);
}
#else
__device__ inline float fdot2(half2v a, half2v b, float c) {
    return (float)a.x * (float)b.x + (float)a.y * (float)b.y + c;
}
#endif

__device__ inline half2v bch2(unsigned u) { return __builtin_bit_cast(half2v, u); }
__device__ inline unsigned pkh2(float lo, float hi) {
    half2v h; h.x = (_Float16)lo; h.y = (_Float16)hi;   // v_cvt_f16_f32 (RTN)
    return __builtin_bit_cast(unsigned, h);
}

// Routing pass. R7-VERBATIM (proven: 56 us/pass, 52 VGPR, 0 bank conflicts,
// clean partial stores). W staged per-n in LDS as fp16 (8 KB/slice, double-
// buffered), x tile fp16, u_hat via v_dot2_f32_f16 (fp32 accumulate).
// Swizzled W layout: chunk (l = j*2+hp, pp) at slot pp*64 + ((l+pp)&63).
// XCD swizzle (verified R4: FETCH 139->26 MB): 8 bc-sharers share blockIdx&7.
// Lessons: R5/R6 = no hoisted index arrays / no unroll pragmas / BT=2 only;
// R8 = cooperative launch unsupported by harness.
template<int LOGITS, int ATOMIC>
__global__ __launch_bounds__(512, 4)
void route_k(const float* __restrict__ x, const float* __restrict__ W,
             const float* __restrict__ OS, float* __restrict__ S)
{
    __shared__ uint4 wbuf[2][512];   // 2 x 8 KB fp16 W double buffer
    __shared__ uint4 xs[BB * BN];    // 8 KB fp16 x tile: [b][n] -> 8 halves

    const int tid  = threadIdx.x;
    const int wave = tid >> 6;
    const int lane = tid & 63;

    const int id  = blockIdx.x;
    const int xcd = id & 7;
    const int bc  = (id >> 3) & 7;
    const int nch = id >> 6;               // 0..7
    const int nc  = xcd + 8 * nch;         // 0..63
    const int b0  = bc * BB;
    const int n0  = nc * BN;
    const int j   = lane >> 1;
    const int hp  = lane & 1;              // p-half

    // ---- stage x tile as fp16: thread t -> (b = t>>5, n = t&31) ----
    {
        const int b = tid >> 5, n = tid & 31;
        const float4* src = reinterpret_cast<const float4*>(
            x + ((size_t)(b0 + b) * Nn + n0 + n) * Dd);
        float4 a = src[0], c4 = src[1];
        uint4 o;
        o.x = pkh2(a.x, a.y);  o.y = pkh2(a.z, a.w);
        o.z = pkh2(c4.x, c4.y); o.w = pkh2(c4.z, c4.w);
        xs[b * BN + n] = o;
    }

    // ---- W staging: thread t -> (j = t>>4, p = t&15); 2 float4 -> 1 uint4 ----
    const float4* Wg = reinterpret_cast<const float4*>(W);
    const int sj = tid >> 4;          // j
    const int sp = tid & 15;          // p
    const int sl = sj * 2 + (sp >> 3);          // l for this chunk
    const int spp = sp & 7;                     // pp
    const int wslot = spp * 64 + ((sl + spp) & 63);

    float4 sta, stb;
    auto load_slice = [&](int n) {
        const size_t base = (size_t)n * 32 + sp * 2 + (size_t)sj * ((size_t)Nn * 32);
        sta = Wg[base];
        stb = Wg[base + 1];
    };
    auto store_slice = [&](int buf) {
        uint4 o;
        o.x = pkh2(sta.x, sta.y);  o.y = pkh2(sta.z, sta.w);
        o.z = pkh2(stb.x, stb.y);  o.w = pkh2(stb.z, stb.w);
        wbuf[buf][wslot] = o;
    };

    // Output-sum fragment for logits
    float osum[BT][8];
    if (LOGITS) {
        #pragma unroll
        for (int bb = 0; bb < BT; ++bb) {
            const float4* op = reinterpret_cast<const float4*>(
                OS + ((size_t)(b0 + wave * BT + bb) * Jj + j) * Pp + hp * 8);
            float4 a = op[0], b4 = op[1];
            osum[bb][0] = a.x;  osum[bb][1] = a.y;  osum[bb][2] = a.z;  osum[bb][3] = a.w;
            osum[bb][4] = b4.x; osum[bb][5] = b4.y; osum[bb][6] = b4.z; osum[bb][7] = b4.w;
        }
    }

    float Sa[BT][8];
    #pragma unroll
    for (int bb = 0; bb < BT; ++bb)
        #pragma unroll
        for (int pp = 0; pp < 8; ++pp) Sa[bb][pp] = 0.f;

    load_slice(n0);
    store_slice(0);
    __syncthreads();

    const uint4* xw = xs + (size_t)(wave * BT) * BN;   // this wave's x rows

    for (int nn = 0; nn < BN; ++nn) {
        if (nn + 1 < BN) load_slice(n0 + nn + 1);  // prefetch next slice to regs
        const int buf = nn & 1;

        // x rows (LDS broadcast, one b128 per batch): 8 halves = 4 half2
        half2v x01[BT], x23[BT], x45[BT], x67[BT];
        #pragma unroll
        for (int bb = 0; bb < BT; ++bb) {
            uint4 xr = xw[(size_t)bb * BN + nn];
            x01[bb] = bch2(xr.x); x23[bb] = bch2(xr.y);
            x45[bb] = bch2(xr.z); x67[bb] = bch2(xr.w);
        }

        // u_hat via fdot2 (f16 inputs, fp32 accumulate); no hadds needed
        float uh[BT][8];
        #pragma unroll
        for (int pp = 0; pp < 8; ++pp) {
            uint4 wv = wbuf[buf][pp * 64 + ((lane + pp) & 63)];
            half2v w01 = bch2(wv.x), w23 = bch2(wv.y);
            half2v w45 = bch2(wv.z), w67 = bch2(wv.w);
            #pragma unroll
            for (int bb = 0; bb < BT; ++bb) {
                float acc = fdot2(w01, x01[bb], 0.f);
                acc = fdot2(w23, x23[bb], acc);
                acc = fdot2(w45, x45[bb], acc);
                acc = fdot2(w67, x67[bb], acc);
                uh[bb][pp] = acc;
            }
        }

        if (!LOGITS) {
            #pragma unroll
            for (int bb = 0; bb < BT; ++bb)
                #pragma unroll
                for (int pp = 0; pp < 8; ++pp) Sa[bb][pp] += uh[bb][pp];
        } else {
            #pragma unroll
            for (int bb = 0; bb < BT; ++bb) {
                float lg = 0.f;
                #pragma unroll
                for (int pp = 0; pp < 8; ++pp)
                    lg = fmaf(osum[bb][pp], uh[bb][pp], lg);
                lg += __shfl_xor(lg, 1, 64);   // merge p-halves: full 16-p dot
                // softmax over j (no max-subtract; |lg| small): butterfly
                float e = __expf(lg);
                float se = e;
                #pragma unroll
                for (int mk = 2; mk <= 32; mk <<= 1)
                    se += __shfl_xor(se, mk, 64);
                float c = e * __builtin_amdgcn_rcpf(se);
                #pragma unroll
                for (int pp = 0; pp < 8; ++pp)
                    Sa[bb][pp] = fmaf(c, uh[bb][pp], Sa[bb][pp]);
            }
        }

        if (nn + 1 < BN) {
            store_slice((nn + 1) & 1);
            __syncthreads();
        }
    }

    // ---- flush block-partial S ----
    #pragma unroll
    for (int bb = 0; bb < BT; ++bb) {
        const size_t off = ((size_t)(b0 + wave * BT + bb) * Jj + j) * Pp + hp * 8;
        if (ATOMIC) {
            float* spd = S + off;
            #pragma unroll
            for (int pp = 0; pp < 8; ++pp) atomicAdd(spd + pp, Sa[bb][pp]);
        } else {
            float4* dst = reinterpret_cast<float4*>(S + (size_t)nc * SZ + off);
            dst[0] = make_float4(Sa[bb][0], Sa[bb][1], Sa[bb][2], Sa[bb][3]);
            dst[1] = make_float4(Sa[bb][4], Sa[bb][5], Sa[bb][6], Sa[bb][7]);
        }
    }
}

// Reduce nparts partial S slices, then squash.
// mode 0: OS = v; 1: OS += v; 2: out = v.
// R9: re-gridded 256 blocks x 64 threads (one float4/thread) so the 16.8 MB
// partial read spreads over all 256 CUs instead of 64 (was ~10 us, now ~3).
__global__ void reduce_squash_k(const float* __restrict__ Sp, int nparts,
                                float scale, float* __restrict__ OS,
                                float* __restrict__ out, int mode)
{
    const int t = blockIdx.x * 64 + threadIdx.x;   // 0..16383
    const float4* sp = reinterpret_cast<const float4*>(Sp);
    float4 a = make_float4(0.f, 0.f, 0.f, 0.f);
    #pragma unroll 8
    for (int s = 0; s < nparts; ++s) {
        float4 v = sp[(size_t)s * (SZ / 4) + t];
        a.x += v.x; a.y += v.y; a.z += v.z; a.w += v.w;
    }
    a.x *= scale; a.y *= scale; a.z *= scale; a.w *= scale;
    float s2 = a.x * a.x + a.y * a.y + a.z * a.z + a.w * a.w;
    s2 += __shfl_xor(s2, 1, 64);   // 16 p = 4 consecutive threads
    s2 += __shfl_xor(s2, 2, 64);
    const float g = s2 / ((1.f + s2) * sqrtf(s2 + 1e-7f));
    float4 v = make_float4(g * a.x, g * a.y, g * a.z, g * a.w);
    if (mode == 0) {
        reinterpret_cast<float4*>(OS)[t] = v;
    } else if (mode == 1) {
        float4 o = reinterpret_cast<float4*>(OS)[t];
        o.x += v.x; o.y += v.y; o.z += v.z; o.w += v.w;
        reinterpret_cast<float4*>(OS)[t] = o;
    } else {
        reinterpret_cast<float4*>(out)[t] = v;
    }
}

extern "C" void kernel_launch(void* const* d_in, const int* in_sizes, int n_in,
                              void* d_out, int out_size, void* d_ws, size_t ws_size,
                              hipStream_t stream)
{
    const float* x = (const float*)d_in[0];   // [128, 2048, 8]
    const float* W = (const float*)d_in[1];   // [32, 2048, 16, 8]
    float* out = (float*)d_out;               // [128, 32, 16]

    const bool part = ws_size >= (size_t)(NNC + 1) * SZ * sizeof(float); // 16.9 MB
    dim3 rg(GRID), rb(512);
    dim3 sg(SZ / 4 / 64), sb(64);             // 256 blocks x 64 threads

    if (part) {
        float* Sp = (float*)d_ws;                 // [64][65536] partials
        float* OS = Sp + (size_t)NNC * SZ;        // running output sum

        route_k<0, 0><<<rg, rb, 0, stream>>>(x, W, nullptr, Sp);
        reduce_squash_k<<<sg, sb, 0, stream>>>(Sp, NNC, 1.f / Jj, OS, out, 0);

        route_k<1, 0><<<rg, rb, 0, stream>>>(x, W, OS, Sp);
        reduce_squash_k<<<sg, sb, 0, stream>>>(Sp, NNC, 1.f, OS, out, 1);

        route_k<1, 0><<<rg, rb, 0, stream>>>(x, W, OS, Sp);
        reduce_squash_k<<<sg, sb, 0, stream>>>(Sp, NNC, 1.f, OS, out, 2);
    } else {
        float* S  = (float*)d_ws;
        float* OS = S + SZ;
        const size_t Sbytes = (size_t)SZ * sizeof(float);

        hipMemsetAsync(S, 0, Sbytes, stream);
        route_k<0, 1><<<rg, rb, 0, stream>>>(x, W, nullptr, S);
        reduce_squash_k<<<sg, sb, 0, stream>>>(S, 1, 1.f / Jj, OS, out, 0);

        hipMemsetAsync(S, 0, Sbytes, stream);
        route_k<1, 1><<<rg, rb, 0, stream>>>(x, W, OS, S);
        reduce_squash_k<<<sg, sb, 0, stream>>>(S, 1, 1.f, OS, out, 1);

        hipMemsetAsync(S, 0, Sbytes, stream);
        route_k<1, 1><<<rg, rb, 0, stream>>>(x, W, OS, S);
        reduce_squash_k<<<sg, sb, 0, stream>>>(S, 1, 1.f, OS, out, 2);
    }
}